// Round 1
// 999.035 us; speedup vs baseline: 1.0078x; 1.0078x over previous
//
#include <hip/hip_runtime.h>
#include <cstdint>
#include <cstddef>

#define HD 128
#define EDGED 16
#define NODED 64
#define LN_EPS 1e-5f

typedef __bf16 bf16x8 __attribute__((ext_vector_type(8)));
typedef float  f32x4  __attribute__((ext_vector_type(4)));

__device__ __forceinline__ float gelu_exact(float x) {
    return 0.5f * x * (1.0f + erff(x * 0.7071067811865475f));
}

// fp32 -> bf16 hi/lo split (a ~= hi + lo, lo captures the rounding residual)
__global__ void wconv_k(const float* __restrict__ in, __bf16* __restrict__ hi,
                        __bf16* __restrict__ lo, int n) {
    int i = blockIdx.x * blockDim.x + threadIdx.x;
    if (i < n) {
        float v = in[i];
        __bf16 h = (__bf16)v;
        hi[i] = h;
        lo[i] = (__bf16)(v - (float)h);
    }
}

// ---------------- CSR build ----------------

__global__ void hist_k(const int* __restrict__ ei, int* __restrict__ cnt, int E) {
    int e = blockIdx.x * blockDim.x + threadIdx.x;
    if (e < E) atomicAdd(&cnt[ei[E + e]], 1);
}

__global__ void scan1_k(const int* __restrict__ in, int* __restrict__ out,
                        int* __restrict__ bsum, int n) {
    __shared__ int lds[256];
    int t = threadIdx.x;
    int i = blockIdx.x * 256 + t;
    int v = (i < n) ? in[i] : 0;
    lds[t] = v;
    __syncthreads();
#pragma unroll
    for (int o = 1; o < 256; o <<= 1) {
        int u = (t >= o) ? lds[t - o] : 0;
        __syncthreads();
        lds[t] += u;
        __syncthreads();
    }
    if (i < n) out[i] = lds[t] - v;
    if (t == 255) bsum[blockIdx.x] = lds[255];
}

__global__ void scan2_k(const int* __restrict__ bsum, int* __restrict__ boff, int nb) {
    __shared__ int lds[256];
    int t = threadIdx.x;
    int v = (t < nb) ? bsum[t] : 0;
    lds[t] = v;
    __syncthreads();
#pragma unroll
    for (int o = 1; o < 256; o <<= 1) {
        int u = (t >= o) ? lds[t - o] : 0;
        __syncthreads();
        lds[t] += u;
        __syncthreads();
    }
    if (t < nb) boff[t] = lds[t] - v;
}

// adds block offsets; also emits the scatter cursor copy (saves a d2d memcpy)
__global__ void scan3_k(int* __restrict__ rs, int* __restrict__ cursor,
                        const int* __restrict__ boff, int n, int E) {
    int i = blockIdx.x * 256 + threadIdx.x;
    if (i < n) {
        int v = rs[i] + boff[blockIdx.x];
        rs[i] = v;
        cursor[i] = v;
    }
    if (i == 0) rs[n] = E;
}

__global__ void scatter_k(const int* __restrict__ ei, int* __restrict__ cursor,
                          int2* __restrict__ es, int E) {
    int e = blockIdx.x * blockDim.x + threadIdx.x;
    if (e < E) {
        int dst = ei[E + e];
        int slot = atomicAdd(&cursor[dst], 1);
        es[slot] = make_int2(ei[e], e);
    }
}

// ---------------- edge-LN precompute (+ fused self-loop embed) ----------------
// Per layer l: wm[k]=mean_c W[c][k]; bm=mean(b); Wp=W-wm; bp=b-bm.
// Wg[k][c] = Wp[c][k]*g[c]; bg[c] = bp[c]*g[c]
// M[k][j] = sum_c Wp[c][k]*Wp[c][j]; v[k]=2*sum_c Wp[c][k]*bp[c]; s0=sum bp^2
// => 128*var(attr a) = a^T M a + v.a + s0 (no 128-wide reduce per edge).
// Tail: embeds the learned self-loop attr for this layer into slv3[l].
__global__ void prep_k(const float* __restrict__ edge_W, const float* __restrict__ edge_b,
                       const float* __restrict__ edge_g, const float* __restrict__ edge_be,
                       const float* __restrict__ sl_attr, float* __restrict__ Wg3,
                       float* __restrict__ bg3, float* __restrict__ M3,
                       float* __restrict__ v3, float* __restrict__ s03,
                       float* __restrict__ slv3)
{
    const int l = blockIdx.x;
    const float* W = edge_W + (size_t)l * HD * EDGED;
    const float* b = edge_b + l * HD;
    const float* g = edge_g + l * HD;
    __shared__ float Wp[HD * EDGED];
    __shared__ float bp[HD];
    __shared__ float wm[EDGED];
    __shared__ float Msh[256];
    __shared__ float vsh[EDGED];
    __shared__ float ash[EDGED];
    __shared__ float bmS, s0sh;
    const int t = threadIdx.x;
#pragma unroll
    for (int m = 0; m < 8; ++m) Wp[m * 256 + t] = W[m * 256 + t];
    __syncthreads();
    if (t < EDGED) {
        float s = 0.f;
        for (int c = 0; c < HD; ++c) s += Wp[c * EDGED + t];
        wm[t] = s * (1.f / HD);
    } else if (t == EDGED) {
        float s = 0.f;
        for (int c = 0; c < HD; ++c) s += b[c];
        bmS = s * (1.f / HD);
    }
    __syncthreads();
    if (t < HD) bp[t] = b[t] - bmS;
    __syncthreads();
#pragma unroll
    for (int m = 0; m < 8; ++m) {
        int idx = m * 256 + t;
        int c = idx >> 4, k = idx & 15;
        float val = Wp[idx] - wm[k];
        Wp[idx] = val;
        Wg3[(size_t)l * 2048 + k * HD + c] = val * g[c];
    }
    if (t < HD) bg3[l * HD + t] = bp[t] * g[t];
    __syncthreads();
    {
        int k = t >> 4, j = t & 15;
        float s = 0.f;
        for (int c = 0; c < HD; ++c) s += Wp[c * EDGED + k] * Wp[c * EDGED + j];
        Msh[t] = s;
        M3[l * 256 + t] = s;
    }
    if (t < EDGED) {
        float s = 0.f;
        for (int c = 0; c < HD; ++c) s += Wp[c * EDGED + t] * bp[c];
        vsh[t] = 2.f * s;
        v3[l * EDGED + t] = 2.f * s;
        ash[t] = sl_attr[l * EDGED + t];
    } else if (t == EDGED) {
        float s = 0.f;
        for (int c = 0; c < HD; ++c) s += bp[c] * bp[c];
        s0sh = s;
        s03[l] = s;
    }
    __syncthreads();
    // self-loop embed: out_c = ((Wp.a)*g + bg)*inv + bet, relu
    if (t < HD) {
        float q = s0sh;
#pragma unroll
        for (int k = 0; k < EDGED; ++k) {
            float tk = vsh[k];
#pragma unroll
            for (int j = 0; j < EDGED; ++j) tk = fmaf(Msh[k * 16 + j], ash[j], tk);
            q = fmaf(ash[k], tk, q);
        }
        float inv = rsqrtf(q * (1.f / HD) + LN_EPS);
        float y = 0.f;
#pragma unroll
        for (int k = 0; k < EDGED; ++k) y = fmaf(Wp[t * EDGED + k], ash[k], y);
        slv3[l * HD + t] = fmaxf(fmaf(fmaf(y, g[t], bg3[l * HD + t]), inv, edge_be[l * HD + t]), 0.f);
    }
}

// Per CSR slot: gather attr row once, emit rsqrt(var+eps) for all 3 layers.
// Also emits the attr row PERMUTED into slot order (attr_p) and the src node
// id (srcp) so the pull kernel reads pure contiguous streams.
__launch_bounds__(256)
__global__ void einv_k(const int2* __restrict__ es, const float* __restrict__ eattr,
                       const float* __restrict__ M3, const float* __restrict__ v3,
                       const float* __restrict__ s03, float* __restrict__ einv,
                       float* __restrict__ attr_p, int* __restrict__ srcp, int E)
{
    __shared__ float Ms[3 * 256];
    __shared__ float vs[3 * 16];
    __shared__ float s0s[4];
    const int t = threadIdx.x;
    for (int i = t; i < 768; i += 256) Ms[i] = M3[i];
    if (t < 48) vs[t] = v3[t];
    if (t < 3) s0s[t] = s03[t];
    __syncthreads();
    int slot = blockIdx.x * 256 + t;
    if (slot >= E) return;
    int2 se = es[slot];
    srcp[slot] = se.x;
    const float4* ap = (const float4*)(eattr + (size_t)se.y * EDGED);
    float4 A0 = ap[0], A1 = ap[1], A2 = ap[2], A3 = ap[3];
    float4* op = (float4*)(attr_p + (size_t)slot * EDGED);
    op[0] = A0; op[1] = A1; op[2] = A2; op[3] = A3;
    float a[16] = {A0.x, A0.y, A0.z, A0.w, A1.x, A1.y, A1.z, A1.w,
                   A2.x, A2.y, A2.z, A2.w, A3.x, A3.y, A3.z, A3.w};
#pragma unroll
    for (int l = 0; l < 3; ++l) {
        float q = s0s[l];
#pragma unroll
        for (int k = 0; k < 16; ++k) {
            const float* Mr = &Ms[l * 256 + k * 16];
            float tk = vs[l * 16 + k];
#pragma unroll
            for (int j = 0; j < 16; ++j) tk = fmaf(Mr[j], a[j], tk);
            q = fmaf(a[k], tk, q);
        }
        einv[(size_t)l * E + slot] = rsqrtf(q * (1.f / HD) + LN_EPS);
    }
}

// ---------------- MFMA GEMM v2: bf16 hi/lo inputs, reg double-buffer --------
// A pre-split to bf16 hi/lo [M][K]; W pre-split [NC][K]. Wave: 32 rows x 64
// cols (RG=2, NT=4); block 128 rows; gridDim.y = NC/64 col tiles. K-loop
// prefetches step s+1's A/B frags before MFMAing step s (latency hiding).
// acc = hi*hi + hi*lo + lo*hi (~fp32 accuracy). Output fp32 or bf16 hi/lo.
template<int K, int NC, int ACT, int STATS, int OUTBF>
__launch_bounds__(256)
__global__ void mgemm_k(const __bf16* __restrict__ Ahi, const __bf16* __restrict__ Alo,
                        const __bf16* __restrict__ Whi, const __bf16* __restrict__ Wlo,
                        const float* __restrict__ bias, float* __restrict__ C,
                        __bf16* __restrict__ Chi, __bf16* __restrict__ Clo,
                        int M, float* __restrict__ stats)
{
    constexpr int RG = 2;
    constexpr int NT = 4;
    constexpr int NK = K / 32;
    __shared__ float st_lds[2][64];

    const int t    = threadIdx.x;
    const int lane = t & 63;
    const int wv   = t >> 6;
    const int ln15 = lane & 15;
    const int quad = lane >> 4;
    const int row_base = blockIdx.x * 128 + wv * 32;
    const int col0 = blockIdx.y * 64;

    f32x4 acc[RG][NT];
#pragma unroll
    for (int g = 0; g < RG; ++g)
#pragma unroll
        for (int nt = 0; nt < NT; ++nt)
#pragma unroll
            for (int r = 0; r < 4; ++r) acc[g][nt][r] = 0.f;

    size_t arow[RG];
#pragma unroll
    for (int g = 0; g < RG; ++g) {
        int row = row_base + g * 16 + ln15;
        row = row < M ? row : M - 1;          // clamp: junk values, store masked
        arow[g] = (size_t)row * K + quad * 8;
    }
    size_t brow[NT];
#pragma unroll
    for (int nt = 0; nt < NT; ++nt)
        brow[nt] = (size_t)(col0 + nt * 16 + ln15) * K + quad * 8;

    bf16x8 a0h[RG], a0l[RG], a1h[RG], a1l[RG];
    bf16x8 b0h[NT], b0l[NT], b1h[NT], b1l[NT];

#define LD_A(kc, AH, AL) { \
    _Pragma("unroll") \
    for (int g = 0; g < RG; ++g) { \
        AH[g] = *(const bf16x8*)(Ahi + arow[g] + (kc)); \
        AL[g] = *(const bf16x8*)(Alo + arow[g] + (kc)); \
    } }
#define LD_B(kc, BH, BL) { \
    _Pragma("unroll") \
    for (int nt = 0; nt < NT; ++nt) { \
        BH[nt] = *(const bf16x8*)(Whi + brow[nt] + (kc)); \
        BL[nt] = *(const bf16x8*)(Wlo + brow[nt] + (kc)); \
    } }
#define DO_MFMA(AH, AL, BH, BL) { \
    _Pragma("unroll") \
    for (int nt = 0; nt < NT; ++nt) { \
        _Pragma("unroll") \
        for (int g = 0; g < RG; ++g) { \
            acc[g][nt] = __builtin_amdgcn_mfma_f32_16x16x32_bf16(AH[g], BH[nt], acc[g][nt], 0, 0, 0); \
            acc[g][nt] = __builtin_amdgcn_mfma_f32_16x16x32_bf16(AH[g], BL[nt], acc[g][nt], 0, 0, 0); \
            acc[g][nt] = __builtin_amdgcn_mfma_f32_16x16x32_bf16(AL[g], BH[nt], acc[g][nt], 0, 0, 0); \
        } } }

    LD_A(0, a0h, a0l);
    LD_B(0, b0h, b0l);
    for (int s = 0; s < NK; s += 2) {
        LD_A((s + 1) * 32, a1h, a1l);
        LD_B((s + 1) * 32, b1h, b1l);
        DO_MFMA(a0h, a0l, b0h, b0l);
        if (s + 2 < NK) {
            LD_A((s + 2) * 32, a0h, a0l);
            LD_B((s + 2) * 32, b0h, b0l);
        }
        DO_MFMA(a1h, a1l, b1h, b1l);
    }
#undef LD_A
#undef LD_B
#undef DO_MFMA

    if (STATS) {
        if (t < 64) { st_lds[0][t] = 0.f; st_lds[1][t] = 0.f; }
        __syncthreads();
    }

    float bv[NT];
#pragma unroll
    for (int nt = 0; nt < NT; ++nt) bv[nt] = bias[col0 + nt * 16 + ln15];

    float s1[NT], s2[NT];
#pragma unroll
    for (int nt = 0; nt < NT; ++nt) { s1[nt] = 0.f; s2[nt] = 0.f; }

#pragma unroll
    for (int g = 0; g < RG; ++g)
#pragma unroll
        for (int r = 0; r < 4; ++r) {
            int row = row_base + g * 16 + quad * 4 + r;
            if (row < M) {
#pragma unroll
                for (int nt = 0; nt < NT; ++nt) {
                    float v = acc[g][nt][r] + bv[nt];
                    if (ACT == 1) v = gelu_exact(v);
                    size_t ci = (size_t)row * NC + col0 + nt * 16 + ln15;
                    if (OUTBF) {
                        __bf16 hh = (__bf16)v;
                        Chi[ci] = hh;
                        Clo[ci] = (__bf16)(v - (float)hh);
                    } else {
                        C[ci] = v;
                    }
                    if (STATS) { s1[nt] += v; s2[nt] += v * v; }
                }
            }
        }

    if (STATS) {
#pragma unroll
        for (int nt = 0; nt < NT; ++nt) {
            atomicAdd(&st_lds[0][nt * 16 + ln15], s1[nt]);
            atomicAdd(&st_lds[1][nt * 16 + ln15], s2[nt]);
        }
        __syncthreads();
        if (t < 64) {
            atomicAdd(&stats[col0 + t],      st_lds[0][t]);
            atomicAdd(&stats[HD + col0 + t], st_lds[1][t]);
        }
    }
}

// LayerNorm(+ReLU) over rows of 128, one wave per node
__global__ void ln_relu_k(const float* __restrict__ y, const float* __restrict__ gam,
                          const float* __restrict__ bet, float* __restrict__ h, int N)
{
    int lane = threadIdx.x & 63;
    int c0 = lane * 2;
    float2 g2 = *(const float2*)&gam[c0];
    float2 b2 = *(const float2*)&bet[c0];
    int wid = (blockIdx.x * blockDim.x + threadIdx.x) >> 6;
    int nw  = (gridDim.x * blockDim.x) >> 6;
    for (int n = wid; n < N; n += nw) {
        float2 v = *(const float2*)&y[(size_t)n * HD + c0];
        float s = v.x + v.y;
        float q = v.x * v.x + v.y * v.y;
#pragma unroll
        for (int o = 32; o > 0; o >>= 1) { s += __shfl_xor(s, o, 64); q += __shfl_xor(q, o, 64); }
        float mu  = s * (1.f / 128.f);
        float inv = rsqrtf(q * (1.f / 128.f) - mu * mu + LN_EPS);
        float2 r;
        r.x = fmaxf(fmaf((v.x - mu) * inv, g2.x, b2.x), 0.f);
        r.y = fmaxf(fmaf((v.y - mu) * inv, g2.y, b2.y), 0.f);
        *(float2*)&h[(size_t)n * HD + c0] = r;
    }
}

// ---------------- pull aggregation v4: one wave per node -------------------
// lane owns channel pair {2*lane, 2*lane+1} -> each h-row gather is ONE
// dwordx2 per lane (wave covers the full 512B row). Edge loop unrolled x4
// with all 4 src/einv shuffles + h-row loads hoisted ahead of the FMA blocks
// (4x memory-level parallelism). Attr comes from a slot-permuted stream
// (attr_p, written by einv_k) so staging is a straight contiguous copy with
// no eid shuffle. Writes aggr as bf16 hi/lo packed pairs.
__launch_bounds__(256)
__global__ void pull4_k(const float* __restrict__ h, const int* __restrict__ srcp,
                        const int* __restrict__ rs, const float* __restrict__ attr_p,
                        const float* __restrict__ einv, const float* __restrict__ slv,
                        const float* __restrict__ Wg, const float* __restrict__ bg,
                        const float* __restrict__ bet, __bf16* __restrict__ Ahi,
                        __bf16* __restrict__ Alo, int N)
{
    __shared__ float alds_all[4][64 * EDGED];   // 16 KB: per-wave attr staging
    const int t = threadIdx.x;
    const int lane = t & 63;
    const int wv = t >> 6;
    float* alds = alds_all[wv];

    const int c0 = lane * 2;
    float w0[16], w1[16];
#pragma unroll
    for (int k = 0; k < 16; ++k) {
        float2 wp = *(const float2*)&Wg[k * HD + c0];
        w0[k] = wp.x; w1[k] = wp.y;
    }
    const float2 bgv = *(const float2*)&bg[c0];
    const float2 btv = *(const float2*)&bet[c0];

    const int n = (blockIdx.x << 2) + wv;
    if (n >= N) return;

    const float2 hself = *(const float2*)&h[(size_t)n * HD + c0];
    const float2 slvv  = *(const float2*)&slv[c0];
    float acc0 = hself.x + slvv.x;
    float acc1 = hself.y + slvv.y;

    const int beg = rs[n], end = rs[n + 1];
    for (int s0 = beg; s0 < end; s0 += 64) {
        int m = end - s0; if (m > 64) m = 64;
        int   srcv = 0;
        float ivv  = 0.f;
        if (lane < m) { srcv = srcp[s0 + lane]; ivv = einv[s0 + lane]; }
        // stage attrs: contiguous stream copy, predicated on idx < 4m
        const float4* src4 = (const float4*)(attr_p + (size_t)s0 * EDGED);
#pragma unroll
        for (int it = 0; it < 4; ++it) {
            int idx = (it << 6) + lane;
            if (idx < (m << 2)) *(float4*)&alds[idx << 2] = src4[idx];
        }
        asm volatile("s_waitcnt lgkmcnt(0)" ::: "memory");

#define EDGE_BODY(JJ, IVJ, HVJ) { \
            const float* ar = &alds[(JJ) * EDGED]; \
            float4 A0 = *(const float4*)ar,       A1 = *(const float4*)(ar + 4); \
            float4 A2 = *(const float4*)(ar + 8), A3 = *(const float4*)(ar + 12); \
            float a[16] = {A0.x, A0.y, A0.z, A0.w, A1.x, A1.y, A1.z, A1.w, \
                           A2.x, A2.y, A2.z, A2.w, A3.x, A3.y, A3.z, A3.w}; \
            float p0 = bgv.x, q0 = 0.f, p1 = bgv.y, q1 = 0.f; \
            _Pragma("unroll") \
            for (int k = 0; k < 16; k += 2) { \
                p0 = fmaf(a[k],     w0[k],     p0); \
                q0 = fmaf(a[k + 1], w0[k + 1], q0); \
                p1 = fmaf(a[k],     w1[k],     p1); \
                q1 = fmaf(a[k + 1], w1[k + 1], q1); \
            } \
            acc0 += fmaxf(fmaf(p0 + q0, IVJ, btv.x), 0.f) + HVJ.x; \
            acc1 += fmaxf(fmaf(p1 + q1, IVJ, btv.y), 0.f) + HVJ.y; \
        }

        int j = 0;
        for (; j + 4 <= m; j += 4) {
            int s_0 = __shfl(srcv, j,     64);
            int s_1 = __shfl(srcv, j + 1, 64);
            int s_2 = __shfl(srcv, j + 2, 64);
            int s_3 = __shfl(srcv, j + 3, 64);
            float i0 = __shfl(ivv, j,     64);
            float i1 = __shfl(ivv, j + 1, 64);
            float i2 = __shfl(ivv, j + 2, 64);
            float i3 = __shfl(ivv, j + 3, 64);
            float2 h0 = *(const float2*)&h[(size_t)s_0 * HD + c0];
            float2 h1 = *(const float2*)&h[(size_t)s_1 * HD + c0];
            float2 h2 = *(const float2*)&h[(size_t)s_2 * HD + c0];
            float2 h3 = *(const float2*)&h[(size_t)s_3 * HD + c0];
            EDGE_BODY(j,     i0, h0);
            EDGE_BODY(j + 1, i1, h1);
            EDGE_BODY(j + 2, i2, h2);
            EDGE_BODY(j + 3, i3, h3);
        }
        for (; j < m; ++j) {
            int s_  = __shfl(srcv, j, 64);
            float ij = __shfl(ivv, j, 64);
            float2 hj = *(const float2*)&h[(size_t)s_ * HD + c0];
            EDGE_BODY(j, ij, hj);
        }
#undef EDGE_BODY
    }
    __bf16 b0 = (__bf16)acc0, b1 = (__bf16)acc1;
    union { __bf16 b[2]; unsigned u; } ph, pl;
    ph.b[0] = b0;
    ph.b[1] = b1;
    pl.b[0] = (__bf16)(acc0 - (float)b0);
    pl.b[1] = (__bf16)(acc1 - (float)b1);
    *(unsigned*)&Ahi[(size_t)n * HD + c0] = ph.u;
    *(unsigned*)&Alo[(size_t)n * HD + c0] = pl.u;
}

// BatchNorm apply from accumulated column sums; optional ReLU
__global__ void bn_k(const float* __restrict__ hl, const float* __restrict__ stats,
                     const float* __restrict__ gam, const float* __restrict__ bet,
                     float* __restrict__ out, int total4, float invN, int relu)
{
    int idx = blockIdx.x * blockDim.x + threadIdx.x;
    if (idx < total4) {
        int c4 = idx & 31;
        float4 x  = ((const float4*)hl)[idx];
        float4 s1 = ((const float4*)stats)[c4];
        float4 s2 = ((const float4*)stats)[32 + c4];
        float4 g  = ((const float4*)gam)[c4];
        float4 b  = ((const float4*)bet)[c4];
        float4 r;
        {
            float m = s1.x * invN; float v = s2.x * invN - m * m;
            r.x = fmaf((x.x - m) * rsqrtf(v + LN_EPS), g.x, b.x);
        }
        {
            float m = s1.y * invN; float v = s2.y * invN - m * m;
            r.y = fmaf((x.y - m) * rsqrtf(v + LN_EPS), g.y, b.y);
        }
        {
            float m = s1.z * invN; float v = s2.z * invN - m * m;
            r.z = fmaf((x.z - m) * rsqrtf(v + LN_EPS), g.z, b.z);
        }
        {
            float m = s1.w * invN; float v = s2.w * invN - m * m;
            r.w = fmaf((x.w - m) * rsqrtf(v + LN_EPS), g.w, b.w);
        }
        if (relu) {
            r.x = fmaxf(r.x, 0.f); r.y = fmaxf(r.y, 0.f);
            r.z = fmaxf(r.z, 0.f); r.w = fmaxf(r.w, 0.f);
        }
        ((float4*)out)[idx] = r;
    }
}

extern "C" void kernel_launch(void* const* d_in, const int* in_sizes, int n_in,
                              void* d_out, int out_size, void* d_ws, size_t ws_size,
                              hipStream_t stream)
{
    const float* x       = (const float*)d_in[0];
    const int*   ei      = (const int*)d_in[1];
    const float* eattr   = (const float*)d_in[2];
    const float* node_W  = (const float*)d_in[3];
    const float* node_b  = (const float*)d_in[4];
    const float* node_g  = (const float*)d_in[5];
    const float* node_be = (const float*)d_in[6];
    const float* edge_W  = (const float*)d_in[7];
    const float* edge_b  = (const float*)d_in[8];
    const float* edge_g  = (const float*)d_in[9];
    const float* edge_be = (const float*)d_in[10];
    const float* sl_attr = (const float*)d_in[11];
    const float* W1      = (const float*)d_in[12];
    const float* b1      = (const float*)d_in[13];
    const float* W2      = (const float*)d_in[14];
    const float* b2      = (const float*)d_in[15];
    const float* bn_g    = (const float*)d_in[16];
    const float* bn_b    = (const float*)d_in[17];

    const int N = in_sizes[0] / NODED;
    const int E = in_sizes[1] / 2;

    // explicit 16B-aligned workspace layout
    char* base = (char*)d_ws;
    size_t off = 0;
    auto take = [&](size_t nbytes) -> void* {
        void* p = base + off;
        off = (off + nbytes + 15) & ~(size_t)15;
        return p;
    };
    float*  h      = (float*)take((size_t)N * HD * 4);
    float*  z      = (float*)take((size_t)N * HD * 4);     // node-embed pre-LN (fp32)
    __bf16* aghi   = (__bf16*)take((size_t)N * HD * 2);    // aggr bf16 hi
    __bf16* aglo   = (__bf16*)take((size_t)N * HD * 2);
    __bf16* zhi    = (__bf16*)take((size_t)N * 256 * 2);   // mlp1 out bf16 hi
    __bf16* zlo    = (__bf16*)take((size_t)N * 256 * 2);
    __bf16* xhi    = (__bf16*)take((size_t)N * NODED * 2);
    __bf16* xlo    = (__bf16*)take((size_t)N * NODED * 2);
    float*  slv3   = (float*)take(3 * HD * 4);
    float*  stats  = (float*)take(3 * 256 * 4);
    int*    cnt    = (int*)take((size_t)N * 4);
    int*    cursor = (int*)take((size_t)N * 4);
    int*    bsum   = (int*)take(256 * 4);
    int*    boff   = (int*)take(256 * 4);
    int*    rs     = (int*)take(((size_t)N + 2) * 4);
    int2*   es     = (int2*)take((size_t)E * 8);
    float*  einv   = (float*)take((size_t)3 * E * 4);
    float*  attr_p = (float*)take((size_t)E * EDGED * 4);  // slot-permuted attrs
    int*    srcp   = (int*)take((size_t)E * 4);            // slot-permuted src ids
    float*  Wg3    = (float*)take(3 * 2048 * 4);
    float*  bg3    = (float*)take(3 * HD * 4);
    float*  M3     = (float*)take(3 * 256 * 4);
    float*  v3     = (float*)take(3 * 16 * 4);
    float*  s03    = (float*)take(4 * 4);
    __bf16* nWhi   = (__bf16*)take((size_t)HD * NODED * 2);
    __bf16* nWlo   = (__bf16*)take((size_t)HD * NODED * 2);
    __bf16* W1hi   = (__bf16*)take((size_t)3 * 256 * HD * 2);
    __bf16* W1lo   = (__bf16*)take((size_t)3 * 256 * HD * 2);
    __bf16* W2hi   = (__bf16*)take((size_t)3 * HD * 256 * 2);
    __bf16* W2lo   = (__bf16*)take((size_t)3 * HD * 256 * 2);

    // bf16 hi/lo splits: weights ([N][K] row-major already) and x
    wconv_k<<<(HD * NODED + 255) / 256, 256, 0, stream>>>(node_W, nWhi, nWlo, HD * NODED);
    wconv_k<<<(3 * 256 * HD + 255) / 256, 256, 0, stream>>>(W1, W1hi, W1lo, 3 * 256 * HD);
    wconv_k<<<(3 * 256 * HD + 255) / 256, 256, 0, stream>>>(W2, W2hi, W2lo, 3 * 256 * HD);
    wconv_k<<<((int)((size_t)N * NODED + 255) / 256), 256, 0, stream>>>(x, xhi, xlo, N * NODED);

    // edge-LN precompute + self-loop embed (all 3 layers)
    prep_k<<<3, 256, 0, stream>>>(edge_W, edge_b, edge_g, edge_be, sl_attr,
                                  Wg3, bg3, M3, v3, s03, slv3);

    // ---- CSR build ----
    const int eblocks = (E + 255) / 256;
    const int nblocks = (N + 255) / 256;
    hipMemsetAsync(cnt, 0, (size_t)N * sizeof(int), stream);
    hist_k<<<eblocks, 256, 0, stream>>>(ei, cnt, E);
    scan1_k<<<nblocks, 256, 0, stream>>>(cnt, rs, bsum, N);
    scan2_k<<<1, 256, 0, stream>>>(bsum, boff, nblocks);
    scan3_k<<<nblocks, 256, 0, stream>>>(rs, cursor, boff, N, E);
    scatter_k<<<eblocks, 256, 0, stream>>>(ei, cursor, es, E);

    // per-slot inv-std for all 3 layers + permuted attr/src streams
    einv_k<<<eblocks, 256, 0, stream>>>(es, eattr, M3, v3, s03, einv, attr_p, srcp, E);

    const int total4  = N * (HD / 4);
    const int vblocks = (total4 + 255) / 256;
    const int pblocks = (N + 3) / 4;
    const int gb128   = (N + 127) / 128;

    // node embed: Linear (MFMA) -> LN -> ReLU
    mgemm_k<NODED, HD, 0, 0, 0><<<dim3(gb128, 2), 256, 0, stream>>>(
        xhi, xlo, nWhi, nWlo, node_b, z, nullptr, nullptr, N, nullptr);
    ln_relu_k<<<pblocks, 256, 0, stream>>>(z, node_g, node_be, h, N);

    hipMemsetAsync(stats, 0, 3 * 256 * sizeof(float), stream);

    for (int l = 0; l < 3; ++l) {
        pull4_k<<<pblocks, 256, 0, stream>>>(h, srcp, rs, attr_p,
                                             einv + (size_t)l * E,
                                             slv3 + l * HD, Wg3 + (size_t)l * 2048,
                                             bg3 + l * HD, edge_be + l * HD,
                                             aghi, aglo, N);

        mgemm_k<HD, 256, 1, 0, 1><<<dim3(gb128, 4), 256, 0, stream>>>(
            aghi, aglo, W1hi + (size_t)l * 256 * HD, W1lo + (size_t)l * 256 * HD,
            b1 + l * 256, nullptr, zhi, zlo, N, nullptr);

        mgemm_k<256, HD, 0, 1, 0><<<dim3(gb128, 2), 256, 0, stream>>>(
            zhi, zlo, W2hi + (size_t)l * HD * 256, W2lo + (size_t)l * HD * 256,
            b2 + l * HD, (float*)d_out, nullptr, nullptr, N, stats + l * 256);

        bn_k<<<vblocks, 256, 0, stream>>>((const float*)d_out, stats + l * 256,
                                          bn_g + l * HD, bn_b + l * HD,
                                          (l < 2) ? h : (float*)d_out, total4, 1.f / N, (l < 2) ? 1 : 0);
    }
}

// Round 3
// 927.425 us; speedup vs baseline: 1.0856x; 1.0772x over previous
//
#include <hip/hip_runtime.h>
#include <cstdint>
#include <cstddef>

#define HD 128
#define EDGED 16
#define NODED 64
#define LN_EPS 1e-5f

typedef __bf16 bf16x8 __attribute__((ext_vector_type(8)));
typedef float  f32x4  __attribute__((ext_vector_type(4)));
typedef _Float16 half2v __attribute__((ext_vector_type(2)));
typedef _Float16 half4v __attribute__((ext_vector_type(4)));

__device__ __forceinline__ float gelu_exact(float x) {
    return 0.5f * x * (1.0f + erff(x * 0.7071067811865475f));
}

// fp32 -> bf16 hi/lo split (a ~= hi + lo, lo captures the rounding residual)
__global__ void wconv_k(const float* __restrict__ in, __bf16* __restrict__ hi,
                        __bf16* __restrict__ lo, int n) {
    int i = blockIdx.x * blockDim.x + threadIdx.x;
    if (i < n) {
        float v = in[i];
        __bf16 h = (__bf16)v;
        hi[i] = h;
        lo[i] = (__bf16)(v - (float)h);
    }
}

// ---------------- CSR build ----------------

__global__ void hist_k(const int* __restrict__ ei, int* __restrict__ cnt, int E) {
    int e = blockIdx.x * blockDim.x + threadIdx.x;
    if (e < E) atomicAdd(&cnt[ei[E + e]], 1);
}

__global__ void scan1_k(const int* __restrict__ in, int* __restrict__ out,
                        int* __restrict__ bsum, int n) {
    __shared__ int lds[256];
    int t = threadIdx.x;
    int i = blockIdx.x * 256 + t;
    int v = (i < n) ? in[i] : 0;
    lds[t] = v;
    __syncthreads();
#pragma unroll
    for (int o = 1; o < 256; o <<= 1) {
        int u = (t >= o) ? lds[t - o] : 0;
        __syncthreads();
        lds[t] += u;
        __syncthreads();
    }
    if (i < n) out[i] = lds[t] - v;
    if (t == 255) bsum[blockIdx.x] = lds[255];
}

__global__ void scan2_k(const int* __restrict__ bsum, int* __restrict__ boff, int nb) {
    __shared__ int lds[256];
    int t = threadIdx.x;
    int v = (t < nb) ? bsum[t] : 0;
    lds[t] = v;
    __syncthreads();
#pragma unroll
    for (int o = 1; o < 256; o <<= 1) {
        int u = (t >= o) ? lds[t - o] : 0;
        __syncthreads();
        lds[t] += u;
        __syncthreads();
    }
    if (t < nb) boff[t] = lds[t] - v;
}

// adds block offsets; also emits the scatter cursor copy (saves a d2d memcpy)
__global__ void scan3_k(int* __restrict__ rs, int* __restrict__ cursor,
                        const int* __restrict__ boff, int n, int E) {
    int i = blockIdx.x * 256 + threadIdx.x;
    if (i < n) {
        int v = rs[i] + boff[blockIdx.x];
        rs[i] = v;
        cursor[i] = v;
    }
    if (i == 0) rs[n] = E;
}

__global__ void scatter_k(const int* __restrict__ ei, int* __restrict__ cursor,
                          int2* __restrict__ es, int E) {
    int e = blockIdx.x * blockDim.x + threadIdx.x;
    if (e < E) {
        int dst = ei[E + e];
        int slot = atomicAdd(&cursor[dst], 1);
        es[slot] = make_int2(ei[e], e);
    }
}

// ---------------- edge-LN precompute (+ fused self-loop embed) ----------------
// Per layer l: wm[k]=mean_c W[c][k]; bm=mean(b); Wp=W-wm; bp=b-bm.
// Wg[k][c] = Wp[c][k]*g[c]; bg[c] = bp[c]*g[c]
// M[k][j] = sum_c Wp[c][k]*Wp[c][j]; v[k]=2*sum_c Wp[c][k]*bp[c]; s0=sum bp^2
// => 128*var(attr a) = a^T M a + v.a + s0 (no 128-wide reduce per edge).
// Tail: embeds the learned self-loop attr for this layer into slv3[l].
__global__ void prep_k(const float* __restrict__ edge_W, const float* __restrict__ edge_b,
                       const float* __restrict__ edge_g, const float* __restrict__ edge_be,
                       const float* __restrict__ sl_attr, float* __restrict__ Wg3,
                       float* __restrict__ bg3, float* __restrict__ M3,
                       float* __restrict__ v3, float* __restrict__ s03,
                       float* __restrict__ slv3)
{
    const int l = blockIdx.x;
    const float* W = edge_W + (size_t)l * HD * EDGED;
    const float* b = edge_b + l * HD;
    const float* g = edge_g + l * HD;
    __shared__ float Wp[HD * EDGED];
    __shared__ float bp[HD];
    __shared__ float wm[EDGED];
    __shared__ float Msh[256];
    __shared__ float vsh[EDGED];
    __shared__ float ash[EDGED];
    __shared__ float bmS, s0sh;
    const int t = threadIdx.x;
#pragma unroll
    for (int m = 0; m < 8; ++m) Wp[m * 256 + t] = W[m * 256 + t];
    __syncthreads();
    if (t < EDGED) {
        float s = 0.f;
        for (int c = 0; c < HD; ++c) s += Wp[c * EDGED + t];
        wm[t] = s * (1.f / HD);
    } else if (t == EDGED) {
        float s = 0.f;
        for (int c = 0; c < HD; ++c) s += b[c];
        bmS = s * (1.f / HD);
    }
    __syncthreads();
    if (t < HD) bp[t] = b[t] - bmS;
    __syncthreads();
#pragma unroll
    for (int m = 0; m < 8; ++m) {
        int idx = m * 256 + t;
        int c = idx >> 4, k = idx & 15;
        float val = Wp[idx] - wm[k];
        Wp[idx] = val;
        Wg3[(size_t)l * 2048 + k * HD + c] = val * g[c];
    }
    if (t < HD) bg3[l * HD + t] = bp[t] * g[t];
    __syncthreads();
    {
        int k = t >> 4, j = t & 15;
        float s = 0.f;
        for (int c = 0; c < HD; ++c) s += Wp[c * EDGED + k] * Wp[c * EDGED + j];
        Msh[t] = s;
        M3[l * 256 + t] = s;
    }
    if (t < EDGED) {
        float s = 0.f;
        for (int c = 0; c < HD; ++c) s += Wp[c * EDGED + t] * bp[c];
        vsh[t] = 2.f * s;
        v3[l * EDGED + t] = 2.f * s;
        ash[t] = sl_attr[l * EDGED + t];
    } else if (t == EDGED) {
        float s = 0.f;
        for (int c = 0; c < HD; ++c) s += bp[c] * bp[c];
        s0sh = s;
        s03[l] = s;
    }
    __syncthreads();
    // self-loop embed: out_c = ((Wp.a)*g + bg)*inv + bet, relu
    if (t < HD) {
        float q = s0sh;
#pragma unroll
        for (int k = 0; k < EDGED; ++k) {
            float tk = vsh[k];
#pragma unroll
            for (int j = 0; j < EDGED; ++j) tk = fmaf(Msh[k * 16 + j], ash[j], tk);
            q = fmaf(ash[k], tk, q);
        }
        float inv = rsqrtf(q * (1.f / HD) + LN_EPS);
        float y = 0.f;
#pragma unroll
        for (int k = 0; k < EDGED; ++k) y = fmaf(Wp[t * EDGED + k], ash[k], y);
        slv3[l * HD + t] = fmaxf(fmaf(fmaf(y, g[t], bg3[l * HD + t]), inv, edge_be[l * HD + t]), 0.f);
    }
}

// Per CSR slot: gather attr row once, emit rsqrt(var+eps) for all 3 layers.
// Also emits the attr row PERMUTED into slot order (attr_p) and the src node
// id (srcp) so the pull kernel reads pure contiguous streams.
__launch_bounds__(256)
__global__ void einv_k(const int2* __restrict__ es, const float* __restrict__ eattr,
                       const float* __restrict__ M3, const float* __restrict__ v3,
                       const float* __restrict__ s03, float* __restrict__ einv,
                       float* __restrict__ attr_p, int* __restrict__ srcp, int E)
{
    __shared__ float Ms[3 * 256];
    __shared__ float vs[3 * 16];
    __shared__ float s0s[4];
    const int t = threadIdx.x;
    for (int i = t; i < 768; i += 256) Ms[i] = M3[i];
    if (t < 48) vs[t] = v3[t];
    if (t < 3) s0s[t] = s03[t];
    __syncthreads();
    int slot = blockIdx.x * 256 + t;
    if (slot >= E) return;
    int2 se = es[slot];
    srcp[slot] = se.x;
    const float4* ap = (const float4*)(eattr + (size_t)se.y * EDGED);
    float4 A0 = ap[0], A1 = ap[1], A2 = ap[2], A3 = ap[3];
    float4* op = (float4*)(attr_p + (size_t)slot * EDGED);
    op[0] = A0; op[1] = A1; op[2] = A2; op[3] = A3;
    float a[16] = {A0.x, A0.y, A0.z, A0.w, A1.x, A1.y, A1.z, A1.w,
                   A2.x, A2.y, A2.z, A2.w, A3.x, A3.y, A3.z, A3.w};
#pragma unroll
    for (int l = 0; l < 3; ++l) {
        float q = s0s[l];
#pragma unroll
        for (int k = 0; k < 16; ++k) {
            const float* Mr = &Ms[l * 256 + k * 16];
            float tk = vs[l * 16 + k];
#pragma unroll
            for (int j = 0; j < 16; ++j) tk = fmaf(Mr[j], a[j], tk);
            q = fmaf(a[k], tk, q);
        }
        einv[(size_t)l * E + slot] = rsqrtf(q * (1.f / HD) + LN_EPS);
    }
}

// ---------------- MFMA GEMM v2: bf16 hi/lo inputs, reg double-buffer --------
// A pre-split to bf16 hi/lo [M][K]; W pre-split [NC][K]. Wave: 32 rows x 64
// cols (RG=2, NT=4); block 128 rows; gridDim.y = NC/64 col tiles. K-loop
// prefetches step s+1's A/B frags before MFMAing step s (latency hiding).
// acc = hi*hi + hi*lo + lo*hi (~fp32 accuracy). Output fp32 or bf16 hi/lo.
template<int K, int NC, int ACT, int STATS, int OUTBF>
__launch_bounds__(256)
__global__ void mgemm_k(const __bf16* __restrict__ Ahi, const __bf16* __restrict__ Alo,
                        const __bf16* __restrict__ Whi, const __bf16* __restrict__ Wlo,
                        const float* __restrict__ bias, float* __restrict__ C,
                        __bf16* __restrict__ Chi, __bf16* __restrict__ Clo,
                        int M, float* __restrict__ stats)
{
    constexpr int RG = 2;
    constexpr int NT = 4;
    constexpr int NK = K / 32;
    __shared__ float st_lds[2][64];

    const int t    = threadIdx.x;
    const int lane = t & 63;
    const int wv   = t >> 6;
    const int ln15 = lane & 15;
    const int quad = lane >> 4;
    const int row_base = blockIdx.x * 128 + wv * 32;
    const int col0 = blockIdx.y * 64;

    f32x4 acc[RG][NT];
#pragma unroll
    for (int g = 0; g < RG; ++g)
#pragma unroll
        for (int nt = 0; nt < NT; ++nt)
#pragma unroll
            for (int r = 0; r < 4; ++r) acc[g][nt][r] = 0.f;

    size_t arow[RG];
#pragma unroll
    for (int g = 0; g < RG; ++g) {
        int row = row_base + g * 16 + ln15;
        row = row < M ? row : M - 1;          // clamp: junk values, store masked
        arow[g] = (size_t)row * K + quad * 8;
    }
    size_t brow[NT];
#pragma unroll
    for (int nt = 0; nt < NT; ++nt)
        brow[nt] = (size_t)(col0 + nt * 16 + ln15) * K + quad * 8;

    bf16x8 a0h[RG], a0l[RG], a1h[RG], a1l[RG];
    bf16x8 b0h[NT], b0l[NT], b1h[NT], b1l[NT];

#define LD_A(kc, AH, AL) { \
    _Pragma("unroll") \
    for (int g = 0; g < RG; ++g) { \
        AH[g] = *(const bf16x8*)(Ahi + arow[g] + (kc)); \
        AL[g] = *(const bf16x8*)(Alo + arow[g] + (kc)); \
    } }
#define LD_B(kc, BH, BL) { \
    _Pragma("unroll") \
    for (int nt = 0; nt < NT; ++nt) { \
        BH[nt] = *(const bf16x8*)(Whi + brow[nt] + (kc)); \
        BL[nt] = *(const bf16x8*)(Wlo + brow[nt] + (kc)); \
    } }
#define DO_MFMA(AH, AL, BH, BL) { \
    _Pragma("unroll") \
    for (int nt = 0; nt < NT; ++nt) { \
        _Pragma("unroll") \
        for (int g = 0; g < RG; ++g) { \
            acc[g][nt] = __builtin_amdgcn_mfma_f32_16x16x32_bf16(AH[g], BH[nt], acc[g][nt], 0, 0, 0); \
            acc[g][nt] = __builtin_amdgcn_mfma_f32_16x16x32_bf16(AH[g], BL[nt], acc[g][nt], 0, 0, 0); \
            acc[g][nt] = __builtin_amdgcn_mfma_f32_16x16x32_bf16(AL[g], BH[nt], acc[g][nt], 0, 0, 0); \
        } } }

    LD_A(0, a0h, a0l);
    LD_B(0, b0h, b0l);
    for (int s = 0; s < NK; s += 2) {
        LD_A((s + 1) * 32, a1h, a1l);
        LD_B((s + 1) * 32, b1h, b1l);
        DO_MFMA(a0h, a0l, b0h, b0l);
        if (s + 2 < NK) {
            LD_A((s + 2) * 32, a0h, a0l);
            LD_B((s + 2) * 32, b0h, b0l);
        }
        DO_MFMA(a1h, a1l, b1h, b1l);
    }
#undef LD_A
#undef LD_B
#undef DO_MFMA

    if (STATS) {
        if (t < 64) { st_lds[0][t] = 0.f; st_lds[1][t] = 0.f; }
        __syncthreads();
    }

    float bv[NT];
#pragma unroll
    for (int nt = 0; nt < NT; ++nt) bv[nt] = bias[col0 + nt * 16 + ln15];

    float s1[NT], s2[NT];
#pragma unroll
    for (int nt = 0; nt < NT; ++nt) { s1[nt] = 0.f; s2[nt] = 0.f; }

#pragma unroll
    for (int g = 0; g < RG; ++g)
#pragma unroll
        for (int r = 0; r < 4; ++r) {
            int row = row_base + g * 16 + quad * 4 + r;
            if (row < M) {
#pragma unroll
                for (int nt = 0; nt < NT; ++nt) {
                    float v = acc[g][nt][r] + bv[nt];
                    if (ACT == 1) v = gelu_exact(v);
                    size_t ci = (size_t)row * NC + col0 + nt * 16 + ln15;
                    if (OUTBF) {
                        __bf16 hh = (__bf16)v;
                        Chi[ci] = hh;
                        Clo[ci] = (__bf16)(v - (float)hh);
                    } else {
                        C[ci] = v;
                    }
                    if (STATS) { s1[nt] += v; s2[nt] += v * v; }
                }
            }
        }

    if (STATS) {
#pragma unroll
        for (int nt = 0; nt < NT; ++nt) {
            atomicAdd(&st_lds[0][nt * 16 + ln15], s1[nt]);
            atomicAdd(&st_lds[1][nt * 16 + ln15], s2[nt]);
        }
        __syncthreads();
        if (t < 64) {
            atomicAdd(&stats[col0 + t],      st_lds[0][t]);
            atomicAdd(&stats[HD + col0 + t], st_lds[1][t]);
        }
    }
}

// LayerNorm(+ReLU) over rows of 128, one wave per node; fp16 output
__global__ void ln_relu_k(const float* __restrict__ y, const float* __restrict__ gam,
                          const float* __restrict__ bet, _Float16* __restrict__ h16, int N)
{
    int lane = threadIdx.x & 63;
    int c0 = lane * 2;
    float2 g2 = *(const float2*)&gam[c0];
    float2 b2 = *(const float2*)&bet[c0];
    int wid = (blockIdx.x * blockDim.x + threadIdx.x) >> 6;
    int nw  = (gridDim.x * blockDim.x) >> 6;
    for (int n = wid; n < N; n += nw) {
        float2 v = *(const float2*)&y[(size_t)n * HD + c0];
        float s = v.x + v.y;
        float q = v.x * v.x + v.y * v.y;
#pragma unroll
        for (int o = 32; o > 0; o >>= 1) { s += __shfl_xor(s, o, 64); q += __shfl_xor(q, o, 64); }
        float mu  = s * (1.f / 128.f);
        float inv = rsqrtf(q * (1.f / 128.f) - mu * mu + LN_EPS);
        half2v r;
        r.x = (_Float16)fmaxf(fmaf((v.x - mu) * inv, g2.x, b2.x), 0.f);
        r.y = (_Float16)fmaxf(fmaf((v.y - mu) * inv, g2.y, b2.y), 0.f);
        *(half2v*)&h16[(size_t)n * HD + c0] = r;
    }
}

// ---------------- pull aggregation v5: persistent waves, fp16 h ------------
// lane owns channel pair {2*lane, 2*lane+1}; h stored fp16 -> each h-row
// gather is ONE dword per lane (wave covers the 256B row). 2048 blocks
// grid-stride nodes: edge-embed weights loaded ONCE per wave (~12 nodes
// amortize the 21-load prologue), no per-node block-retire tail. Edge loop
// unrolled x4 with hoisted src/einv shuffles + h loads (4x MLP). Attr from
// slot-permuted stream; staging is a contiguous copy. Output bf16 hi/lo.
__launch_bounds__(256)
__global__ void pull5_k(const _Float16* __restrict__ h16, const int* __restrict__ srcp,
                        const int* __restrict__ rs, const float* __restrict__ attr_p,
                        const float* __restrict__ einv, const float* __restrict__ slv,
                        const float* __restrict__ Wg, const float* __restrict__ bg,
                        const float* __restrict__ bet, __bf16* __restrict__ Ahi,
                        __bf16* __restrict__ Alo, int N)
{
    __shared__ float alds_all[4][64 * EDGED];   // 16 KB: per-wave attr staging
    const int t = threadIdx.x;
    const int lane = t & 63;
    const int wv = t >> 6;
    float* alds = alds_all[wv];

    const int c0 = lane * 2;
    float w0[16], w1[16];
#pragma unroll
    for (int k = 0; k < 16; ++k) {
        float2 wp = *(const float2*)&Wg[k * HD + c0];
        w0[k] = wp.x; w1[k] = wp.y;
    }
    const float2 bgv  = *(const float2*)&bg[c0];
    const float2 btv  = *(const float2*)&bet[c0];
    const float2 slvv = *(const float2*)&slv[c0];

    const int stride = gridDim.x << 2;
    for (int n = (blockIdx.x << 2) + wv; n < N; n += stride) {
        half2v hs = *(const half2v*)&h16[(size_t)n * HD + c0];
        float acc0 = (float)hs.x + slvv.x;
        float acc1 = (float)hs.y + slvv.y;

        const int beg = rs[n], end = rs[n + 1];
        for (int s0 = beg; s0 < end; s0 += 64) {
            int m = end - s0; if (m > 64) m = 64;
            int   srcv = 0;
            float ivv  = 0.f;
            if (lane < m) { srcv = srcp[s0 + lane]; ivv = einv[s0 + lane]; }
            // stage attrs: contiguous stream copy, predicated on idx < 4m
            const float4* src4 = (const float4*)(attr_p + (size_t)s0 * EDGED);
#pragma unroll
            for (int it = 0; it < 4; ++it) {
                int idx = (it << 6) + lane;
                if (idx < (m << 2)) *(float4*)&alds[idx << 2] = src4[idx];
            }
            asm volatile("s_waitcnt lgkmcnt(0)" ::: "memory");

#define EDGE_BODY(JJ, IVJ, HVJ) { \
            const float* ar = &alds[(JJ) * EDGED]; \
            float4 A0 = *(const float4*)ar,       A1 = *(const float4*)(ar + 4); \
            float4 A2 = *(const float4*)(ar + 8), A3 = *(const float4*)(ar + 12); \
            float a[16] = {A0.x, A0.y, A0.z, A0.w, A1.x, A1.y, A1.z, A1.w, \
                           A2.x, A2.y, A2.z, A2.w, A3.x, A3.y, A3.z, A3.w}; \
            float p0 = bgv.x, q0 = 0.f, p1 = bgv.y, q1 = 0.f; \
            _Pragma("unroll") \
            for (int k = 0; k < 16; k += 2) { \
                p0 = fmaf(a[k],     w0[k],     p0); \
                q0 = fmaf(a[k + 1], w0[k + 1], q0); \
                p1 = fmaf(a[k],     w1[k],     p1); \
                q1 = fmaf(a[k + 1], w1[k + 1], q1); \
            } \
            acc0 += fmaxf(fmaf(p0 + q0, IVJ, btv.x), 0.f) + (float)HVJ.x; \
            acc1 += fmaxf(fmaf(p1 + q1, IVJ, btv.y), 0.f) + (float)HVJ.y; \
        }

            int j = 0;
            for (; j + 4 <= m; j += 4) {
                int s_0 = __shfl(srcv, j,     64);
                int s_1 = __shfl(srcv, j + 1, 64);
                int s_2 = __shfl(srcv, j + 2, 64);
                int s_3 = __shfl(srcv, j + 3, 64);
                float i0 = __shfl(ivv, j,     64);
                float i1 = __shfl(ivv, j + 1, 64);
                float i2 = __shfl(ivv, j + 2, 64);
                float i3 = __shfl(ivv, j + 3, 64);
                half2v h0 = *(const half2v*)&h16[(size_t)s_0 * HD + c0];
                half2v h1 = *(const half2v*)&h16[(size_t)s_1 * HD + c0];
                half2v h2 = *(const half2v*)&h16[(size_t)s_2 * HD + c0];
                half2v h3 = *(const half2v*)&h16[(size_t)s_3 * HD + c0];
                EDGE_BODY(j,     i0, h0);
                EDGE_BODY(j + 1, i1, h1);
                EDGE_BODY(j + 2, i2, h2);
                EDGE_BODY(j + 3, i3, h3);
            }
            for (; j < m; ++j) {
                int s_  = __shfl(srcv, j, 64);
                float ij = __shfl(ivv, j, 64);
                half2v hj = *(const half2v*)&h16[(size_t)s_ * HD + c0];
                EDGE_BODY(j, ij, hj);
            }
#undef EDGE_BODY
        }
        __bf16 b0 = (__bf16)acc0, b1 = (__bf16)acc1;
        union { __bf16 b[2]; unsigned u; } ph, pl;
        ph.b[0] = b0;
        ph.b[1] = b1;
        pl.b[0] = (__bf16)(acc0 - (float)b0);
        pl.b[1] = (__bf16)(acc1 - (float)b1);
        *(unsigned*)&Ahi[(size_t)n * HD + c0] = ph.u;
        *(unsigned*)&Alo[(size_t)n * HD + c0] = pl.u;
    }
}

// BatchNorm apply from accumulated column sums; optional ReLU.
// out16 != null -> write fp16 (h for next layer); else fp32 to out32.
__global__ void bn_k(const float* __restrict__ hl, const float* __restrict__ stats,
                     const float* __restrict__ gam, const float* __restrict__ bet,
                     float* __restrict__ out32, _Float16* __restrict__ out16,
                     int total4, float invN, int relu)
{
    int idx = blockIdx.x * blockDim.x + threadIdx.x;
    if (idx < total4) {
        int c4 = idx & 31;
        float4 x  = ((const float4*)hl)[idx];
        float4 s1 = ((const float4*)stats)[c4];
        float4 s2 = ((const float4*)stats)[32 + c4];
        float4 g  = ((const float4*)gam)[c4];
        float4 b  = ((const float4*)bet)[c4];
        float4 r;
        {
            float m = s1.x * invN; float v = s2.x * invN - m * m;
            r.x = fmaf((x.x - m) * rsqrtf(v + LN_EPS), g.x, b.x);
        }
        {
            float m = s1.y * invN; float v = s2.y * invN - m * m;
            r.y = fmaf((x.y - m) * rsqrtf(v + LN_EPS), g.y, b.y);
        }
        {
            float m = s1.z * invN; float v = s2.z * invN - m * m;
            r.z = fmaf((x.z - m) * rsqrtf(v + LN_EPS), g.z, b.z);
        }
        {
            float m = s1.w * invN; float v = s2.w * invN - m * m;
            r.w = fmaf((x.w - m) * rsqrtf(v + LN_EPS), g.w, b.w);
        }
        if (relu) {
            r.x = fmaxf(r.x, 0.f); r.y = fmaxf(r.y, 0.f);
            r.z = fmaxf(r.z, 0.f); r.w = fmaxf(r.w, 0.f);
        }
        if (out16) {
            half4v o;
            o.x = (_Float16)r.x; o.y = (_Float16)r.y;
            o.z = (_Float16)r.z; o.w = (_Float16)r.w;
            *(half4v*)&out16[(size_t)idx * 4] = o;
        } else {
            ((float4*)out32)[idx] = r;
        }
    }
}

extern "C" void kernel_launch(void* const* d_in, const int* in_sizes, int n_in,
                              void* d_out, int out_size, void* d_ws, size_t ws_size,
                              hipStream_t stream)
{
    const float* x       = (const float*)d_in[0];
    const int*   ei      = (const int*)d_in[1];
    const float* eattr   = (const float*)d_in[2];
    const float* node_W  = (const float*)d_in[3];
    const float* node_b  = (const float*)d_in[4];
    const float* node_g  = (const float*)d_in[5];
    const float* node_be = (const float*)d_in[6];
    const float* edge_W  = (const float*)d_in[7];
    const float* edge_b  = (const float*)d_in[8];
    const float* edge_g  = (const float*)d_in[9];
    const float* edge_be = (const float*)d_in[10];
    const float* sl_attr = (const float*)d_in[11];
    const float* W1      = (const float*)d_in[12];
    const float* b1      = (const float*)d_in[13];
    const float* W2      = (const float*)d_in[14];
    const float* b2      = (const float*)d_in[15];
    const float* bn_g    = (const float*)d_in[16];
    const float* bn_b    = (const float*)d_in[17];

    const int N = in_sizes[0] / NODED;
    const int E = in_sizes[1] / 2;

    // explicit 16B-aligned workspace layout
    char* base = (char*)d_ws;
    size_t off = 0;
    auto take = [&](size_t nbytes) -> void* {
        void* p = base + off;
        off = (off + nbytes + 15) & ~(size_t)15;
        return p;
    };
    _Float16* h16  = (_Float16*)take((size_t)N * HD * 2); // node features (fp16)
    float*  z      = (float*)take((size_t)N * HD * 4);     // node-embed pre-LN (fp32)
    __bf16* aghi   = (__bf16*)take((size_t)N * HD * 2);    // aggr bf16 hi
    __bf16* aglo   = (__bf16*)take((size_t)N * HD * 2);
    __bf16* zhi    = (__bf16*)take((size_t)N * 256 * 2);   // mlp1 out bf16 hi
    __bf16* zlo    = (__bf16*)take((size_t)N * 256 * 2);
    __bf16* xhi    = (__bf16*)take((size_t)N * NODED * 2);
    __bf16* xlo    = (__bf16*)take((size_t)N * NODED * 2);
    float*  slv3   = (float*)take(3 * HD * 4);
    float*  stats  = (float*)take(3 * 256 * 4);
    int*    cnt    = (int*)take((size_t)N * 4);
    int*    cursor = (int*)take((size_t)N * 4);
    int*    bsum   = (int*)take(256 * 4);
    int*    boff   = (int*)take(256 * 4);
    int*    rs     = (int*)take(((size_t)N + 2) * 4);
    int2*   es     = (int2*)take((size_t)E * 8);
    float*  einv   = (float*)take((size_t)3 * E * 4);
    float*  attr_p = (float*)take((size_t)E * EDGED * 4);  // slot-permuted attrs
    int*    srcp   = (int*)take((size_t)E * 4);            // slot-permuted src ids
    float*  Wg3    = (float*)take(3 * 2048 * 4);
    float*  bg3    = (float*)take(3 * HD * 4);
    float*  M3     = (float*)take(3 * 256 * 4);
    float*  v3     = (float*)take(3 * 16 * 4);
    float*  s03    = (float*)take(4 * 4);
    __bf16* nWhi   = (__bf16*)take((size_t)HD * NODED * 2);
    __bf16* nWlo   = (__bf16*)take((size_t)HD * NODED * 2);
    __bf16* W1hi   = (__bf16*)take((size_t)3 * 256 * HD * 2);
    __bf16* W1lo   = (__bf16*)take((size_t)3 * 256 * HD * 2);
    __bf16* W2hi   = (__bf16*)take((size_t)3 * HD * 256 * 2);
    __bf16* W2lo   = (__bf16*)take((size_t)3 * HD * 256 * 2);

    // bf16 hi/lo splits: weights ([N][K] row-major already) and x
    wconv_k<<<(HD * NODED + 255) / 256, 256, 0, stream>>>(node_W, nWhi, nWlo, HD * NODED);
    wconv_k<<<(3 * 256 * HD + 255) / 256, 256, 0, stream>>>(W1, W1hi, W1lo, 3 * 256 * HD);
    wconv_k<<<(3 * 256 * HD + 255) / 256, 256, 0, stream>>>(W2, W2hi, W2lo, 3 * 256 * HD);
    wconv_k<<<((int)((size_t)N * NODED + 255) / 256), 256, 0, stream>>>(x, xhi, xlo, N * NODED);

    // edge-LN precompute + self-loop embed (all 3 layers)
    prep_k<<<3, 256, 0, stream>>>(edge_W, edge_b, edge_g, edge_be, sl_attr,
                                  Wg3, bg3, M3, v3, s03, slv3);

    // ---- CSR build ----
    const int eblocks = (E + 255) / 256;
    const int nblocks = (N + 255) / 256;
    hipMemsetAsync(cnt, 0, (size_t)N * sizeof(int), stream);
    hist_k<<<eblocks, 256, 0, stream>>>(ei, cnt, E);
    scan1_k<<<nblocks, 256, 0, stream>>>(cnt, rs, bsum, N);
    scan2_k<<<1, 256, 0, stream>>>(bsum, boff, nblocks);
    scan3_k<<<nblocks, 256, 0, stream>>>(rs, cursor, boff, N, E);
    scatter_k<<<eblocks, 256, 0, stream>>>(ei, cursor, es, E);

    // per-slot inv-std for all 3 layers + permuted attr/src streams
    einv_k<<<eblocks, 256, 0, stream>>>(es, eattr, M3, v3, s03, einv, attr_p, srcp, E);

    const int total4  = N * (HD / 4);
    const int vblocks = (total4 + 255) / 256;
    const int gb128   = (N + 127) / 128;
    int pgrid = (N + 3) / 4;
    if (pgrid > 2048) pgrid = 2048;           // persistent: 8192 waves

    // node embed: Linear (MFMA) -> LN -> ReLU
    mgemm_k<NODED, HD, 0, 0, 0><<<dim3(gb128, 2), 256, 0, stream>>>(
        xhi, xlo, nWhi, nWlo, node_b, z, nullptr, nullptr, N, nullptr);
    ln_relu_k<<<(N + 3) / 4, 256, 0, stream>>>(z, node_g, node_be, h16, N);

    hipMemsetAsync(stats, 0, 3 * 256 * sizeof(float), stream);

    for (int l = 0; l < 3; ++l) {
        pull5_k<<<pgrid, 256, 0, stream>>>(h16, srcp, rs, attr_p,
                                           einv + (size_t)l * E,
                                           slv3 + l * HD, Wg3 + (size_t)l * 2048,
                                           bg3 + l * HD, edge_be + l * HD,
                                           aghi, aglo, N);

        mgemm_k<HD, 256, 1, 0, 1><<<dim3(gb128, 4), 256, 0, stream>>>(
            aghi, aglo, W1hi + (size_t)l * 256 * HD, W1lo + (size_t)l * 256 * HD,
            b1 + l * 256, nullptr, zhi, zlo, N, nullptr);

        mgemm_k<256, HD, 0, 1, 0><<<dim3(gb128, 2), 256, 0, stream>>>(
            zhi, zlo, W2hi + (size_t)l * HD * 256, W2lo + (size_t)l * HD * 256,
            b2 + l * HD, (float*)d_out, nullptr, nullptr, N, stats + l * 256);

        bn_k<<<vblocks, 256, 0, stream>>>((const float*)d_out, stats + l * 256,
                                          bn_g + l * HD, bn_b + l * HD,
                                          (float*)d_out, (l < 2) ? h16 : nullptr,
                                          total4, 1.f / N, (l < 2) ? 1 : 0);
    }
}